// Round 11
// baseline (1592.315 us; speedup 1.0000x reference)
//
#include <hip/hip_runtime.h>
#include <stdint.h>

#define NN 100000
#define MM 500000
#define FD 128
#define KK 256
#define NHEADS 3
#define NTILES 3907

typedef __attribute__((ext_vector_type(8))) __bf16 bf16x8;
typedef __attribute__((ext_vector_type(4))) float floatx4;

__device__ __forceinline__ float bf2f(unsigned short u) {
    union { uint32_t i; float f; } c; c.i = ((uint32_t)u) << 16; return c.f;
}
__device__ __forceinline__ unsigned short f2bf(float f) {
    union { float f; uint32_t i; } c; c.f = f;
    uint32_t i = c.i;
    return (unsigned short)((i + 0x7FFFu + ((i >> 16) & 1u)) >> 16);
}
// hardware float->bf16 (RNE via v_cvt) for the hot path
__device__ __forceinline__ unsigned short f2bf_hw(float f) {
    __bf16 h = (__bf16)f;
    return __builtin_bit_cast(unsigned short, h);
}
// fast silu (rcp) — used in k_gate (R8 bundle measured net-positive there)
__device__ __forceinline__ float silu(float a) {
    float e = __expf(-a);
    return a * __builtin_amdgcn_rcpf(1.f + e);
}
// exact-division silu — used in k_msg. R9/R10 A/B: rcp version cost k_msg 683->765us
// (VALUBusy 39->22): the div's VALU work hides STAGE latency between issue and
// drain-barrier and staggers the 2 lockstep blocks/CU. Keep the division in k_msg.
__device__ __forceinline__ float silu_div(float a) { return a / (1.f + __expf(-a)); }
__device__ __forceinline__ float fin(float v) {
    return (v == v && fabsf(v) < 1e30f) ? v : 0.f;
}
// async global->LDS, 16B per lane; dest is wave-uniform base + lane*16
__device__ __forceinline__ void gl_lds16(const void* g, void* l) {
    __builtin_amdgcn_global_load_lds(
        (const __attribute__((address_space(1))) unsigned int*)g,
        (__attribute__((address_space(3))) unsigned int*)l, 16, 0, 0);
}
// explicit drain of outstanding global/buffer ops (incl. global_load_lds) before barrier
__device__ __forceinline__ void vm_drain() {
    asm volatile("s_waitcnt vmcnt(0)" ::: "memory");
}
// bijective XCD-chunked block swizzle (m204). Used in k_gate ONLY (pure-gather kernel:
// contiguous node range per XCD = L2 warmth). NOT in k_msg (atomics want contention
// spread across XCDs; default mapping is the proven config for the atomic scatter).
__device__ __forceinline__ int swz_bid(int d, int nwg) {
    int qq = nwg >> 3, rr = nwg & 7;
    int xcd = d & 7, idx = d >> 3;
    int base = (xcd < rr) ? xcd * (qq + 1) : rr * (qq + 1) + (xcd - rr) * qq;
    return base + idx;
}

// =================== zero ===================
__global__ void k_zero(float* __restrict__ p, int nwords) {
    int i = blockIdx.x * 256 + threadIdx.x;
    if (i < nwords) p[i] = 0.f;
}

// =================== cast x (fp32) -> xb (bf16) ===================
__global__ void k_castx(const float* __restrict__ x, unsigned short* __restrict__ xb) {
    int i = blockIdx.x * 256 + threadIdx.x;   // pair index
    if (i < NN * FD / 2) {
        float2 v = ((const float2*)x)[i];
        uint32_t p = (uint32_t)f2bf(v.x) | ((uint32_t)f2bf(v.y) << 16);
        ((uint32_t*)xb)[i] = p;
    }
}

// =================== weight transposes (fp32 src -> bf16 transposed) ===================
__global__ void k_transpose_w1(const float* __restrict__ gw1,
                               const float* __restrict__ mw1,
                               unsigned short* __restrict__ W1t) {
    int idx = blockIdx.x * 256 + threadIdx.x;      // 6*65536
    int j = idx >> 16;
    int rem = idx & 65535;
    int n = rem >> 8, k = rem & 255;
    const float* src = (j < 3) ? (gw1 + (size_t)j * 65536)
                               : (mw1 + (size_t)(j - 3) * 65536);
    W1t[(size_t)idx] = f2bf(src[k * 256 + n]);
}
__global__ void k_transpose_wo(const float* __restrict__ mwo,
                               unsigned short* __restrict__ Wot) {
    int idx = blockIdx.x * 256 + threadIdx.x;      // 3*32768
    int h = idx / 32768;
    int rem = idx % 32768;
    int f = rem >> 8, k = rem & 255;
    Wot[idx] = f2bf(mwo[(size_t)h * 32768 + k * 128 + f]);
}

// =================== CSR build ===================
__global__ void k_hist(const int* __restrict__ idx, int* __restrict__ cnt) {
    int e = blockIdx.x * 256 + threadIdx.x;
    if (e < MM) atomicAdd(&cnt[idx[e]], 1);
}
__global__ void k_scan1(const int* __restrict__ cnt, int* __restrict__ pincl, int* __restrict__ bsum) {
    __shared__ int s[256];
    int t = threadIdx.x;
    int i = blockIdx.x * 256 + t;
    int v = (i < NN) ? cnt[i] : 0;
    s[t] = v; __syncthreads();
    for (int o = 1; o < 256; o <<= 1) {
        int add = (t >= o) ? s[t - o] : 0;
        __syncthreads();
        s[t] += add;
        __syncthreads();
    }
    if (i < NN) pincl[i] = s[t];
    if (t == 255) bsum[blockIdx.x] = s[255];
}
__global__ void k_scan2(const int* __restrict__ bsum, int* __restrict__ boff, int nb) {
    __shared__ int s[512];
    int t = threadIdx.x;
    int v = (t < nb) ? bsum[t] : 0;
    s[t] = v; __syncthreads();
    for (int o = 1; o < 512; o <<= 1) {
        int add = (t >= o) ? s[t - o] : 0;
        __syncthreads();
        s[t] += add;
        __syncthreads();
    }
    if (t < nb) boff[t] = s[t] - v;
}
__global__ void k_scan3(const int* __restrict__ pincl, const int* __restrict__ boff, int* __restrict__ rp) {
    int i = blockIdx.x * 256 + threadIdx.x;
    if (i < NN) rp[i + 1] = pincl[i] + boff[i >> 8];
    if (i == 0) rp[0] = 0;
}
__global__ void k_scatter(const int* __restrict__ self, const int* __restrict__ rp,
                          int* __restrict__ fill, int* __restrict__ elist) {
    int e = blockIdx.x * 256 + threadIdx.x;
    if (e < MM) {
        int n = self[e];
        int pos = atomicAdd(&fill[n], 1);
        elist[rp[n] + pos] = e;
    }
}
__global__ void k_perm(const int* __restrict__ elist, const int* __restrict__ self,
                       const int* __restrict__ nbr, int* __restrict__ selfp, int* __restrict__ nbrp) {
    int i = blockIdx.x * 256 + threadIdx.x;
    if (i < MM) {
        int e = elist[i];
        selfp[i] = self[e];
        nbrp[i] = nbr[e];
    }
}

// =================== colsum of fea (count-weighted node sums, fp32 x) ===================
__global__ void k_colsum(const float* __restrict__ x,
                         const int* __restrict__ cnt_self, const int* __restrict__ cnt_nbr,
                         float* __restrict__ colsum) {
    int t = threadIdx.x;
    int col = t & 127, part = t >> 7;
    const int* cp = part ? cnt_nbr : cnt_self;
    int n0 = blockIdx.x * 512;
    float a = 0.f;
    for (int i = 0; i < 512; i++) {
        int n = n0 + i;
        if (n < NN) {
            float c = (float)cp[n];
            a += c * x[(size_t)n * FD + col];
        }
    }
    atomicAdd(&colsum[part * 128 + col], a);
}

// =================== S diag quadrants via NODE Gram (no gather, 100K rows) ===========
// S11 = sum_n cnt_self[n] x_n x_n^T ; S22 = sum_n cnt_nbr[n] x_n x_n^T
// (regrouped from the edge sum; weight folded into bf16 A-operand, ~2^-9 rel rounding)
#define NCHN 1563   // ceil(NN/64)
#define CPNB 4      // grid.x = 391
__global__ __launch_bounds__(256, 2)
void k_Sn(const unsigned short* __restrict__ xb,
          const int* __restrict__ cnt_self, const int* __restrict__ cnt_nbr,
          float* __restrict__ S) {
    __shared__ unsigned short LT[256][72];   // rows 0..127: weighted feats; 128..255: plain
    const int tid = threadIdx.x;
    const int e_l = tid & 63;
    const int half = tid >> 6;
    const int part = blockIdx.y;            // 0: self counts -> S11 ; 1: nbr counts -> S22
    const int* cp = part ? cnt_nbr : cnt_self;
    const int lane = tid & 63, w = tid >> 6;
    const int lr = lane & 15, q = lane >> 4;

    int cbeg = blockIdx.x * CPNB;
    int cend = cbeg + CPNB; if (cend > NCHN) cend = NCHN;

    floatx4 acc[2][8];
#pragma unroll
    for (int a = 0; a < 2; a++)
#pragma unroll
        for (int b = 0; b < 8; b++)
#pragma unroll
            for (int r = 0; r < 4; r++) acc[a][b][r] = 0.f;

    for (int ch = cbeg; ch < cend; ch++) {
        int n = ch * 64 + e_l;
        union { uint4 v[8]; unsigned short us[64]; } buf;
        if (n < NN) {
            const unsigned short* src = xb + (size_t)n * FD + (half & 1) * 64;
#pragma unroll
            for (int u2 = 0; u2 < 8; u2++) buf.v[u2] = *(const uint4*)(src + u2 * 8);
            if (half < 2) {
                float wgt = (float)cp[n];
#pragma unroll
                for (int j = 0; j < 64; j++) buf.us[j] = f2bf_hw(wgt * bf2f(buf.us[j]));
            }
        } else {
#pragma unroll
            for (int u2 = 0; u2 < 8; u2++) { buf.v[u2].x = 0u; buf.v[u2].y = 0u; buf.v[u2].z = 0u; buf.v[u2].w = 0u; }
        }
        __syncthreads();
#pragma unroll
        for (int j2 = 0; j2 < 64; j2++)
            LT[half * 64 + j2][e_l] = buf.us[j2];
        __syncthreads();
#pragma unroll
        for (int ks = 0; ks < 64; ks += 32) {
            bf16x8 aF[2], bF[8];
#pragma unroll
            for (int mi = 0; mi < 2; mi++)
                aF[mi] = *(const bf16x8*)&LT[w * 32 + mi * 16 + lr][ks + q * 8];
#pragma unroll
            for (int nj = 0; nj < 8; nj++)
                bF[nj] = *(const bf16x8*)&LT[128 + nj * 16 + lr][ks + q * 8];
#pragma unroll
            for (int mi = 0; mi < 2; mi++)
#pragma unroll
                for (int nj = 0; nj < 8; nj++)
                    acc[mi][nj] = __builtin_amdgcn_mfma_f32_16x16x32_bf16(aF[mi], bF[nj], acc[mi][nj], 0, 0, 0);
        }
    }
#pragma unroll
    for (int mi = 0; mi < 2; mi++)
#pragma unroll
        for (int nj = 0; nj < 8; nj++)
#pragma unroll
            for (int r = 0; r < 4; r++) {
                int row = w * 32 + mi * 16 + q * 4 + r + part * 128;
                int col = nj * 16 + lr + part * 128;
                atomicAdd(&S[row * 256 + col], acc[mi][nj][r]);
            }
}

// =================== S12 quadrant via EDGE Gram (single gather pass, CSR-local) ======
// S12 = sum_e x_self(e) x_nbr(e)^T ; S21 written as mirror.
#define NCH 7813
#define CPEB 16     // grid.x = 489
__global__ __launch_bounds__(256, 2)
void k_Se(const unsigned short* __restrict__ xb,
          const int* __restrict__ selfp, const int* __restrict__ nbrp,
          float* __restrict__ S) {
    __shared__ unsigned short LT[256][72];   // rows 0..127: self feats; 128..255: nbr feats
    const int tid = threadIdx.x;
    const int e_l = tid & 63;
    const int half = tid >> 6;
    const int lane = tid & 63, w = tid >> 6;
    const int lr = lane & 15, q = lane >> 4;

    int cbeg = blockIdx.x * CPEB;
    int cend = cbeg + CPEB; if (cend > NCH) cend = NCH;

    floatx4 acc[2][8];
#pragma unroll
    for (int a = 0; a < 2; a++)
#pragma unroll
        for (int b = 0; b < 8; b++)
#pragma unroll
            for (int r = 0; r < 4; r++) acc[a][b][r] = 0.f;

    for (int ch = cbeg; ch < cend; ch++) {
        int e = ch * 64 + e_l;
        union { uint4 v[8]; unsigned short us[64]; } buf;
        if (e < MM) {
            int node = (half < 2) ? selfp[e] : nbrp[e];   // selfp sorted -> near-sequential
            const unsigned short* src = xb + (size_t)node * FD + (half & 1) * 64;
#pragma unroll
            for (int u2 = 0; u2 < 8; u2++) buf.v[u2] = *(const uint4*)(src + u2 * 8);
        } else {
#pragma unroll
            for (int u2 = 0; u2 < 8; u2++) { buf.v[u2].x = 0u; buf.v[u2].y = 0u; buf.v[u2].z = 0u; buf.v[u2].w = 0u; }
        }
        __syncthreads();
#pragma unroll
        for (int j2 = 0; j2 < 64; j2++)
            LT[half * 64 + j2][e_l] = buf.us[j2];
        __syncthreads();
#pragma unroll
        for (int ks = 0; ks < 64; ks += 32) {
            bf16x8 aF[2], bF[8];
#pragma unroll
            for (int mi = 0; mi < 2; mi++)
                aF[mi] = *(const bf16x8*)&LT[w * 32 + mi * 16 + lr][ks + q * 8];
#pragma unroll
            for (int nj = 0; nj < 8; nj++)
                bF[nj] = *(const bf16x8*)&LT[128 + nj * 16 + lr][ks + q * 8];
#pragma unroll
            for (int mi = 0; mi < 2; mi++)
#pragma unroll
                for (int nj = 0; nj < 8; nj++)
                    acc[mi][nj] = __builtin_amdgcn_mfma_f32_16x16x32_bf16(aF[mi], bF[nj], acc[mi][nj], 0, 0, 0);
        }
    }
#pragma unroll
    for (int mi = 0; mi < 2; mi++)
#pragma unroll
        for (int nj = 0; nj < 8; nj++)
#pragma unroll
            for (int r = 0; r < 4; r++) {
                int row = w * 32 + mi * 16 + q * 4 + r;   // self feat i
                int col = nj * 16 + lr;                    // nbr feat j
                float v = acc[mi][nj][r];
                atomicAdd(&S[row * 256 + 128 + col], v);        // S12[i][j]
                atomicAdd(&S[(128 + col) * 256 + row], v);      // S21[j][i]
            }
}

// =================== per-net BN scale/shift from S + colsum ===================
__global__ void k_stats(const float* __restrict__ S, const float* __restrict__ colsum,
                        const unsigned short* __restrict__ W1t,
                        const float* __restrict__ gg, const float* __restrict__ gbe,
                        const float* __restrict__ mg, const float* __restrict__ mbe,
                        float* __restrict__ scaleA, float* __restrict__ shiftA) {
    __shared__ float ws[16][257];
    __shared__ float qq[16], uu[16];
    int t = threadIdx.x;
    int j = blockIdx.y;
    int c0 = blockIdx.x * 16;
    const unsigned short* Wn = W1t + (size_t)j * 65536;
    const float* g    = (j < 3) ? gg + j * 256 : mg + (j - 3) * 256;
    const float* beta = (j < 3) ? gbe + j * 256 : mbe + (j - 3) * 256;
#pragma unroll
    for (int i = 0; i < 16; i++) ws[i][t] = bf2f(Wn[(size_t)(c0 + i) * 256 + t]);
    if (t < 16) { qq[t] = 0.f; uu[t] = 0.f; }
    __syncthreads();
    float vpart[16];
#pragma unroll
    for (int i = 0; i < 16; i++) vpart[i] = 0.f;
    for (int k = 0; k < 256; k++) {
        float s = S[k * 256 + t];          // S symmetric: column read = (S w)_t
#pragma unroll
        for (int i = 0; i < 16; i++) vpart[i] += s * ws[i][k];
    }
    float cs = colsum[t];
    int lane = t & 63;
#pragma unroll
    for (int i = 0; i < 16; i++) {
        float q1 = ws[i][t] * vpart[i];
        float u1 = cs * ws[i][t];
#pragma unroll
        for (int m = 1; m <= 32; m <<= 1) { q1 += __shfl_xor(q1, m); u1 += __shfl_xor(u1, m); }
        if (lane == 0) { atomicAdd(&qq[i], q1); atomicAdd(&uu[i], u1); }
    }
    __syncthreads();
    if (t < 16) {
        int c = c0 + t;
        float mu = fin(uu[t] / (float)MM);
        float var = fmaxf(fin(qq[t] / (float)MM - mu * mu), 0.f);
        float sc = fin(g[c] * rsqrtf(var + 1e-5f));
        scaleA[j * 256 + c] = sc;
        shiftA[j * 256 + c] = fin(beta[c] - mu * sc);
    }
}

// =================== fused gate, ALL 3 HEADS (R3 skeleton + XCD swizzle) =============
__global__ __launch_bounds__(256, 2)
void k_gate(const unsigned short* __restrict__ x,
            const int* __restrict__ selfp, const int* __restrict__ nbrp,
            const unsigned short* __restrict__ W1t,     // gate nets base (3 * 65536)
            const float* __restrict__ scale, const float* __restrict__ shift,  // [3][256]
            const float* __restrict__ wo, const float* __restrict__ bo,        // [3][256], [3]
            float* __restrict__ glog) {                  // [3][MM]
    __shared__ unsigned char Bs[2][16384];   // linear, XOR-swizzled content
    __shared__ float sc[3][256], sh[3][256], wv[3][256];
    __shared__ int nid[128], nidN[128];

    const int tid = threadIdx.x;
    const int m0 = swz_bid(blockIdx.x, NTILES) * 128;
#pragma unroll
    for (int h = 0; h < 3; h++) {
        sc[h][tid] = scale[h * 256 + tid];
        sh[h][tid] = shift[h * 256 + tid];
        wv[h][tid] = wo[h * 256 + tid];
    }
    if (tid < 128) {
        int e = m0 + tid;
        nid[tid]  = (e < MM) ? selfp[e] : 0;
        nidN[tid] = (e < MM) ? nbrp[e] : 0;
    }
    __syncthreads();

    const int lane = tid & 63, w = tid >> 6;
    const int lr = lane & 15, q = lane >> 4;
    const int swz = (lr & 7) << 4;

    // ---- A fragments in registers: rows w*32+mi*16+lr, k = s*32+q*8 ----
    bf16x8 aReg[2][8];
    {
        const unsigned short* bS0 = x + (size_t)nid[w * 32 + lr] * FD;
        const unsigned short* bS1 = x + (size_t)nid[w * 32 + 16 + lr] * FD;
        const unsigned short* bN0 = x + (size_t)nidN[w * 32 + lr] * FD;
        const unsigned short* bN1 = x + (size_t)nidN[w * 32 + 16 + lr] * FD;
#pragma unroll
        for (int s = 0; s < 8; s++) {
            int koff = (s & 3) * 32 + q * 8;
            aReg[0][s] = *(const bf16x8*)(((s < 4) ? bS0 : bN0) + koff);
            aReg[1][s] = *(const bf16x8*)(((s < 4) ? bS1 : bN1) + koff);
        }
    }

    // staging source offsets (bytes): linear dest o -> pre-swizzled source
    uint32_t pre[4];
#pragma unroll
    for (int c = 0; c < 4; c++) {
        int o = (w * 4 + c) * 1024 + lane * 16;
        int r = o >> 7, lc = o & 127;
        pre[c] = (uint32_t)(r * 512 + (lc ^ ((r & 7) << 4)));
    }

    auto STAGE = [&](int t, int b) {
        int hh = t >> 3, rr = t & 7, nh2 = rr >> 2, kc = rr & 3;
        const char* gb = (const char*)(W1t + (size_t)hh * 65536 + (size_t)nh2 * 32768 + kc * 64);
#pragma unroll
        for (int c = 0; c < 4; c++)
            gl_lds16(gb + pre[c], &Bs[b][(w * 4 + c) * 1024]);
    };

    STAGE(0, 0);
    vm_drain();
    __syncthreads();

    int buf = 0, tcur = 0;
    for (int h = 0; h < 3; h++) {
        float dotp[2][4];
#pragma unroll
        for (int mi = 0; mi < 2; mi++)
#pragma unroll
            for (int r = 0; r < 4; r++) dotp[mi][r] = 0.f;

        for (int nh = 0; nh < 2; nh++) {
            floatx4 acc[2][8];
#pragma unroll
            for (int a = 0; a < 2; a++)
#pragma unroll
                for (int b = 0; b < 8; b++)
#pragma unroll
                    for (int r = 0; r < 4; r++) acc[a][b][r] = 0.f;

#pragma unroll
            for (int kc = 0; kc < 4; kc++) {
                if (tcur + 1 < 24) STAGE(tcur + 1, buf ^ 1);
#pragma unroll
                for (int ks = 0; ks < 2; ks++) {
                    bf16x8 bF[8];
#pragma unroll
                    for (int nj = 0; nj < 8; nj++)
                        bF[nj] = *(const bf16x8*)&Bs[buf][(nj * 16 + lr) * 128 + ((ks * 64 + q * 16) ^ swz)];
                    __builtin_amdgcn_s_setprio(1);
#pragma unroll
                    for (int mi = 0; mi < 2; mi++)
#pragma unroll
                        for (int nj = 0; nj < 8; nj++)
                            acc[mi][nj] = __builtin_amdgcn_mfma_f32_16x16x32_bf16(aReg[mi][kc * 2 + ks], bF[nj], acc[mi][nj], 0, 0, 0);
                    __builtin_amdgcn_s_setprio(0);
                }
                vm_drain();
                __syncthreads();
                buf ^= 1; tcur++;
            }
            // fold BN+SiLU+Wo dot into dotp
#pragma unroll
            for (int mi = 0; mi < 2; mi++)
#pragma unroll
                for (int r = 0; r < 4; r++) {
                    float d = 0.f;
#pragma unroll
                    for (int nj = 0; nj < 8; nj++) {
                        int cg = nh * 128 + nj * 16 + lr;
                        float v = acc[mi][nj][r] * sc[h][cg] + sh[h][cg];
                        d += silu(v) * wv[h][cg];
                    }
                    dotp[mi][r] += d;
                }
        }
        float b0 = bo[h];
#pragma unroll
        for (int mi = 0; mi < 2; mi++)
#pragma unroll
            for (int r = 0; r < 4; r++) {
                float v = dotp[mi][r];
                v += __shfl_xor(v, 1); v += __shfl_xor(v, 2);
                v += __shfl_xor(v, 4); v += __shfl_xor(v, 8);
                if (lr == 0) {
                    int row = w * 32 + mi * 16 + q * 4 + r;
                    int e = m0 + row;
                    if (e < MM) glog[(size_t)h * MM + e] = fin(v + b0);
                }
            }
    }
}

// =================== softmax coefficients per node (head-parallel) ===================
__global__ void k_coef(const int* __restrict__ rp, const float* __restrict__ glog,
                       float* __restrict__ coef, const float* __restrict__ ew,
                       const int* __restrict__ nbrp, const float* __restrict__ powp) {
    int n = blockIdx.x * 256 + threadIdx.x;
    if (n >= NN) return;
    int b = rp[n], e = rp[n + 1];
    if (e <= b) return;
    int h = blockIdx.y;
    const float* gl = glog + (size_t)h * MM;
    float* cf = coef + (size_t)h * MM;
    float p = powp[h];
    float gmax = -3.4e38f;
    for (int i = b; i < e; i++) gmax = fmaxf(gmax, gl[i]);
    float den = 0.f;
    for (int i = b; i < e; i++) {
        float wvv = ew[nbrp[i]];
        float u = fin(powf(wvv, p) * __expf(gl[i] - gmax));
        cf[i] = u; den += u;
    }
    float inv = fin(1.f / (den + 1e-10f));
    for (int i = b; i < e; i++) cf[i] = fin(cf[i] * inv);
}

// =================== fused msg, ALL 3 HEADS (exact R3 skeleton incl. div-silu) =======
__global__ __launch_bounds__(256, 2)
void k_msg(const unsigned short* __restrict__ x,
           const int* __restrict__ selfp, const int* __restrict__ nbrp,
           const unsigned short* __restrict__ W1t,       // msg nets base (3 * 65536)
           const float* __restrict__ scale, const float* __restrict__ shift,   // [3][256]
           const unsigned short* __restrict__ Wo2t,      // [3][128 f][256 k]
           const float* __restrict__ bo2,                // [3][128]
           const float* __restrict__ coef,               // [3][MM] perm order
           float* __restrict__ out_acc) {
    __shared__ unsigned char Bs[2][16384];   // linear, XOR-swizzled content
    __shared__ unsigned short ActC[128][72];
    __shared__ float sc[3][256], sh[3][256];
    __shared__ float bvec[3][128], cfs[3][128];
    __shared__ int nid[128], nidN[128];

    const int tid = threadIdx.x;
    const int m0 = blockIdx.x * 128;
#pragma unroll
    for (int h = 0; h < 3; h++) {
        sc[h][tid] = scale[h * 256 + tid];
        sh[h][tid] = shift[h * 256 + tid];
    }
    if (tid < 128) {
        int e = m0 + tid;
        nid[tid]  = (e < MM) ? selfp[e] : -1;
        nidN[tid] = (e < MM) ? nbrp[e] : 0;
#pragma unroll
        for (int h = 0; h < 3; h++) {
            bvec[h][tid] = bo2[h * 128 + tid];
            cfs[h][tid] = (e < MM) ? coef[(size_t)h * MM + e] : 0.f;
        }
    }
    __syncthreads();

    const int lane = tid & 63, w = tid >> 6;
    const int lr = lane & 15, q = lane >> 4;
    const int swz = (lr & 7) << 4;

    // ---- A fragments in registers ----
    bf16x8 aReg[2][8];
    {
        int nS0 = nid[w * 32 + lr];      if (nS0 < 0) nS0 = 0;
        int nS1 = nid[w * 32 + 16 + lr]; if (nS1 < 0) nS1 = 0;
        const unsigned short* bS0 = x + (size_t)nS0 * FD;
        const unsigned short* bS1 = x + (size_t)nS1 * FD;
        const unsigned short* bN0 = x + (size_t)nidN[w * 32 + lr] * FD;
        const unsigned short* bN1 = x + (size_t)nidN[w * 32 + 16 + lr] * FD;
#pragma unroll
        for (int s = 0; s < 8; s++) {
            int koff = (s & 3) * 32 + q * 8;
            aReg[0][s] = *(const bf16x8*)(((s < 4) ? bS0 : bN0) + koff);
            aReg[1][s] = *(const bf16x8*)(((s < 4) ? bS1 : bN1) + koff);
        }
    }

    uint32_t pre[4];
#pragma unroll
    for (int c = 0; c < 4; c++) {
        int o = (w * 4 + c) * 1024 + lane * 16;
        int r = o >> 7, lc = o & 127;
        pre[c] = (uint32_t)(r * 512 + (lc ^ ((r & 7) << 4)));
    }

    // tile t in 0..35: hh = t/12, rr = t%12, nh = rr/6, s6 = rr%6
    // s6<4 -> W1 tile (kc=s6); else Wo2 tile (kc2=s6-4)
    auto STAGE = [&](int t, int b) {
        int hh = t / 12, rr = t % 12, nh2 = rr / 6, s6 = rr % 6;
        const unsigned short* base = (s6 < 4)
            ? (W1t + (size_t)hh * 65536 + (size_t)nh2 * 32768 + s6 * 64)
            : (Wo2t + (size_t)hh * 32768 + nh2 * 128 + (s6 - 4) * 64);
        const char* gb = (const char*)base;
#pragma unroll
        for (int c = 0; c < 4; c++)
            gl_lds16(gb + pre[c], &Bs[b][(w * 4 + c) * 1024]);
    };

    STAGE(0, 0);
    vm_drain();
    __syncthreads();

    floatx4 acc2[2][8];   // combined accumulator over all 3 heads (coef-weighted)
#pragma unroll
    for (int a = 0; a < 2; a++)
#pragma unroll
        for (int b = 0; b < 8; b++)
#pragma unroll
            for (int r = 0; r < 4; r++) acc2[a][b][r] = 0.f;

    int buf = 0, tcur = 0;
    for (int h = 0; h < 3; h++) {
        float cfr[2][4];
#pragma unroll
        for (int mi = 0; mi < 2; mi++)
#pragma unroll
            for (int r = 0; r < 4; r++) cfr[mi][r] = cfs[h][w * 32 + mi * 16 + q * 4 + r];

        for (int nh = 0; nh < 2; nh++) {
            floatx4 acc[2][8];
#pragma unroll
            for (int a = 0; a < 2; a++)
#pragma unroll
                for (int b = 0; b < 8; b++)
#pragma unroll
                    for (int r = 0; r < 4; r++) acc[a][b][r] = 0.f;

#pragma unroll
            for (int kc = 0; kc < 4; kc++) {
                if (tcur + 1 < 36) STAGE(tcur + 1, buf ^ 1);
#pragma unroll
                for (int ks = 0; ks < 2; ks++) {
                    bf16x8 bF[8];
#pragma unroll
                    for (int nj = 0; nj < 8; nj++)
                        bF[nj] = *(const bf16x8*)&Bs[buf][(nj * 16 + lr) * 128 + ((ks * 64 + q * 16) ^ swz)];
                    __builtin_amdgcn_s_setprio(1);
#pragma unroll
                    for (int mi = 0; mi < 2; mi++)
#pragma unroll
                        for (int nj = 0; nj < 8; nj++)
                            acc[mi][nj] = __builtin_amdgcn_mfma_f32_16x16x32_bf16(aReg[mi][kc * 2 + ks], bF[nj], acc[mi][nj], 0, 0, 0);
                    __builtin_amdgcn_s_setprio(0);
                }
                vm_drain();
                __syncthreads();
                buf ^= 1; tcur++;
            }
#pragma unroll
            for (int kc2 = 0; kc2 < 2; kc2++) {
                if (tcur + 1 < 36) STAGE(tcur + 1, buf ^ 1);
                // activations: rows w*32..+31 are written AND read by this wave only
#pragma unroll
                for (int mi = 0; mi < 2; mi++)
#pragma unroll
                    for (int njl = 0; njl < 4; njl++)
#pragma unroll
                        for (int r = 0; r < 4; r++) {
                            int nj = kc2 * 4 + njl;
                            int row = w * 32 + mi * 16 + q * 4 + r;
                            int cg = nh * 128 + nj * 16 + lr;
                            float v = acc[mi][nj][r] * sc[h][cg] + sh[h][cg];
                            ActC[row][njl * 16 + lr] = f2bf_hw(silu_div(v) * cfr[mi][r]);
                        }
#pragma unroll
                for (int ks = 0; ks < 2; ks++) {
                    bf16x8 aF[2], bF[8];
#pragma unroll
                    for (int mi = 0; mi < 2; mi++)
                        aF[mi] = *(const bf16x8*)&ActC[w * 32 + mi * 16 + lr][ks * 32 + q * 8];
#pragma unroll
                    for (int nj = 0; nj < 8; nj++)
                        bF[nj] = *(const bf16x8*)&Bs[buf][(nj * 16 + lr) * 128 + ((ks * 64 + q * 16) ^ swz)];
                    __builtin_amdgcn_s_setprio(1);
#pragma unroll
                    for (int mi = 0; mi < 2; mi++)
#pragma unroll
                        for (int nj = 0; nj < 8; nj++)
                            acc2[mi][nj] = __builtin_amdgcn_mfma_f32_16x16x32_bf16(aF[mi], bF[nj], acc2[mi][nj], 0, 0, 0);
                    __builtin_amdgcn_s_setprio(0);
                }
                vm_drain();
                __syncthreads();
                buf ^= 1; tcur++;
            }
        }
    }
    // ---- epilogue: single combined atomic scatter; bias term = sum_h cf_h[row]*b_h[col]
#pragma unroll
    for (int mi = 0; mi < 2; mi++) {
        int rbase = w * 32 + mi * 16 + q * 4;
        int n0 = nid[rbase], n3 = nid[rbase + 3];
        float c0[3], c1[3], c2[3], c3[3];
#pragma unroll
        for (int h = 0; h < 3; h++) {
            c0[h] = cfs[h][rbase];     c1[h] = cfs[h][rbase + 1];
            c2[h] = cfs[h][rbase + 2]; c3[h] = cfs[h][rbase + 3];
        }
#pragma unroll
        for (int nj = 0; nj < 8; nj++) {
            int col = nj * 16 + lr;
            float b0h = bvec[0][col], b1h = bvec[1][col], b2h = bvec[2][col];
            float v0 = acc2[mi][nj][0] + c0[0] * b0h + c0[1] * b1h + c0[2] * b2h;
            float v1 = acc2[mi][nj][1] + c1[0] * b0h + c1[1] * b1h + c1[2] * b2h;
            float v2 = acc2[mi][nj][2] + c2[0] * b0h + c2[1] * b1h + c2[2] * b2h;
            float v3 = acc2[mi][nj][3] + c3[0] * b0h + c3[1] * b1h + c3[2] * b2h;
            if (n0 == n3) {
                if (n0 >= 0) atomicAdd(&out_acc[(size_t)n0 * FD + col], v0 + v1 + v2 + v3);
            } else {
                int n1 = nid[rbase + 1], n2 = nid[rbase + 2];
                if (n0 >= 0) atomicAdd(&out_acc[(size_t)n0 * FD + col], v0);
                if (n1 >= 0) atomicAdd(&out_acc[(size_t)n1 * FD + col], v1);
                if (n2 >= 0) atomicAdd(&out_acc[(size_t)n2 * FD + col], v2);
                if (n3 >= 0) atomicAdd(&out_acc[(size_t)n3 * FD + col], v3);
            }
        }
    }
}

// =================== final (in place): out = out/3 + x ===================
__global__ void k_finalout(float* __restrict__ out, const float* __restrict__ x) {
    int i = blockIdx.x * 256 + threadIdx.x;
    if (i < NN * FD) out[i] = fin(out[i]) * (1.f / 3.f) + x[i];
}

extern "C" void kernel_launch(void* const* d_in, const int* in_sizes, int n_in,
                              void* d_out, int out_size, void* d_ws, size_t ws_size,
                              hipStream_t stream) {
    const float* ew   = (const float*)d_in[0];
    const float* x    = (const float*)d_in[1];
    const float* gW1  = (const float*)d_in[2];
    const float* gg   = (const float*)d_in[4];
    const float* gbe  = (const float*)d_in[5];
    const float* gWo  = (const float*)d_in[6];
    const float* gbo  = (const float*)d_in[7];
    const float* mW1  = (const float*)d_in[8];
    const float* mg   = (const float*)d_in[10];
    const float* mbe  = (const float*)d_in[11];
    const float* mWo  = (const float*)d_in[12];
    const float* mbo  = (const float*)d_in[13];
    const float* powp = (const float*)d_in[14];
    const int* self_idx = (const int*)d_in[15];
    const int* nbr_idx  = (const int*)d_in[16];
    float* out = (float*)d_out;

    char* ws = (char*)d_ws;
    size_t off = 0;
    auto alloc = [&](size_t bytes) -> void* {
        size_t o = off;
        off += (bytes + 255) & ~(size_t)255;
        return (void*)(ws + o);
    };

    // ---- zero span (contiguous) ----
    float* S       = (float*)alloc(256 * 256 * 4);
    float* colsum  = (float*)alloc(512 * 4);
    int*   cnt     = (int*)alloc((size_t)NN * 4);
    int*   cntn    = (int*)alloc((size_t)NN * 4);
    int*   fill    = (int*)alloc((size_t)NN * 4);
    size_t zero_end = off;
    // ---- rest ----
    unsigned short* xb   = (unsigned short*)alloc((size_t)NN * FD * 2);
    unsigned short* W1t  = (unsigned short*)alloc(6ull * 65536 * 2);
    unsigned short* Wo2t = (unsigned short*)alloc(3ull * 32768 * 2);
    float* scaleA = (float*)alloc(6ull * 256 * 4);
    float* shiftA = (float*)alloc(6ull * 256 * 4);
    int*   rp     = (int*)alloc((size_t)(NN + 1) * 4);
    int*   pincl  = (int*)alloc((size_t)NN * 4);
    int*   bsum   = (int*)alloc(512 * 4);
    int*   boff   = (int*)alloc(512 * 4);
    int*   elist  = (int*)alloc((size_t)MM * 4);
    int*   selfp  = (int*)alloc((size_t)MM * 4);
    int*   nbrp   = (int*)alloc((size_t)MM * 4);
    float* glog   = (float*)alloc(3ull * MM * 4);
    float* coef   = (float*)alloc(3ull * MM * 4);
    if (off > ws_size) return;   // ~47 MB needed

    int zwords = (int)(zero_end / 4);
    k_zero<<<(zwords + 255) / 256, 256, 0, stream>>>(S, zwords);
    k_zero<<<(NN * FD + 255) / 256, 256, 0, stream>>>(out, NN * FD);  // out = accumulator

    k_castx<<<(NN * FD / 2 + 255) / 256, 256, 0, stream>>>(x, xb);
    k_transpose_w1<<<1536, 256, 0, stream>>>(gW1, mW1, W1t);
    k_transpose_wo<<<384, 256, 0, stream>>>(mWo, Wo2t);

    k_hist<<<1954, 256, 0, stream>>>(self_idx, cnt);
    k_hist<<<1954, 256, 0, stream>>>(nbr_idx, cntn);
    int nb1 = (NN + 255) / 256;   // 391
    k_scan1<<<nb1, 256, 0, stream>>>(cnt, pincl, bsum);
    k_scan2<<<1, 512, 0, stream>>>(bsum, boff, nb1);
    k_scan3<<<nb1, 256, 0, stream>>>(pincl, boff, rp);
    k_scatter<<<1954, 256, 0, stream>>>(self_idx, rp, fill, elist);
    k_perm<<<1954, 256, 0, stream>>>(elist, self_idx, nbr_idx, selfp, nbrp);

    k_colsum<<<(NN + 511) / 512, 256, 0, stream>>>(x, cnt, cntn, colsum);
    // S: diag quadrants from node Gram (no gather), off-diag from single edge pass
    k_Sn<<<dim3(391, 2), 256, 0, stream>>>(xb, cnt, cntn, S);
    k_Se<<<489, 256, 0, stream>>>(xb, selfp, nbrp, S);
    k_stats<<<dim3(16, 6), 256, 0, stream>>>(S, colsum, W1t, gg, gbe, mg, mbe, scaleA, shiftA);

    // fused 3-head gate (one dispatch)
    k_gate<<<NTILES, 256, 0, stream>>>(xb, selfp, nbrp, W1t,
                                       scaleA, shiftA, gWo, gbo, glog);
    k_coef<<<dim3(nb1, 3), 256, 0, stream>>>(rp, glog, coef, ew, nbrp, powp);
    // fused 3-head msg (one dispatch, single combined atomic epilogue)
    k_msg<<<NTILES, 256, 0, stream>>>(xb, selfp, nbrp, W1t + 3ull * 65536,
                                      scaleA + 3 * 256, shiftA + 3 * 256,
                                      Wo2t, mbo, coef, out);
    k_finalout<<<(NN * FD + 255) / 256, 256, 0, stream>>>(out, x);
}

// Round 12
// 1498.774 us; speedup vs baseline: 1.0624x; 1.0624x over previous
//
#include <hip/hip_runtime.h>
#include <stdint.h>

#define NN 100000
#define MM 500000
#define FD 128
#define KK 256
#define NHEADS 3
#define NTILES 3907

typedef __attribute__((ext_vector_type(8))) __bf16 bf16x8;
typedef __attribute__((ext_vector_type(4))) float floatx4;

__device__ __forceinline__ float bf2f(unsigned short u) {
    union { uint32_t i; float f; } c; c.i = ((uint32_t)u) << 16; return c.f;
}
__device__ __forceinline__ unsigned short f2bf(float f) {
    union { float f; uint32_t i; } c; c.f = f;
    uint32_t i = c.i;
    return (unsigned short)((i + 0x7FFFu + ((i >> 16) & 1u)) >> 16);
}
// hardware float->bf16 (RNE via v_cvt) for the hot path
__device__ __forceinline__ unsigned short f2bf_hw(float f) {
    __bf16 h = (__bf16)f;
    return __builtin_bit_cast(unsigned short, h);
}
// fast silu (rcp) — used in k_gate (R8 bundle measured net-positive there)
__device__ __forceinline__ float silu(float a) {
    float e = __expf(-a);
    return a * __builtin_amdgcn_rcpf(1.f + e);
}
// exact-division silu — used in k_msg. R9/R10 A/B: rcp version cost k_msg 683->765us
// (VALUBusy 39->22): the div's VALU work hides STAGE latency between issue and
// drain-barrier and staggers the 2 lockstep blocks/CU. Keep the division in k_msg.
__device__ __forceinline__ float silu_div(float a) { return a / (1.f + __expf(-a)); }
__device__ __forceinline__ float fin(float v) {
    return (v == v && fabsf(v) < 1e30f) ? v : 0.f;
}
// async global->LDS, 16B per lane; dest is wave-uniform base + lane*16
__device__ __forceinline__ void gl_lds16(const void* g, void* l) {
    __builtin_amdgcn_global_load_lds(
        (const __attribute__((address_space(1))) unsigned int*)g,
        (__attribute__((address_space(3))) unsigned int*)l, 16, 0, 0);
}
// explicit drain of outstanding global/buffer ops (incl. global_load_lds) before barrier
__device__ __forceinline__ void vm_drain() {
    asm volatile("s_waitcnt vmcnt(0)" ::: "memory");
}
// bijective XCD-chunked block swizzle (m204). Used in k_gate ONLY (pure-gather kernel:
// contiguous node range per XCD = L2 warmth). NOT in k_msg (atomics want contention
// spread across XCDs; default mapping is the proven config for the atomic scatter).
__device__ __forceinline__ int swz_bid(int d, int nwg) {
    int qq = nwg >> 3, rr = nwg & 7;
    int xcd = d & 7, idx = d >> 3;
    int base = (xcd < rr) ? xcd * (qq + 1) : rr * (qq + 1) + (xcd - rr) * qq;
    return base + idx;
}

// =================== zero ===================
__global__ void k_zero(float* __restrict__ p, int nwords) {
    int i = blockIdx.x * 256 + threadIdx.x;
    if (i < nwords) p[i] = 0.f;
}

// =================== cast x (fp32) -> xb (bf16) ===================
__global__ void k_castx(const float* __restrict__ x, unsigned short* __restrict__ xb) {
    int i = blockIdx.x * 256 + threadIdx.x;   // pair index
    if (i < NN * FD / 2) {
        float2 v = ((const float2*)x)[i];
        uint32_t p = (uint32_t)f2bf(v.x) | ((uint32_t)f2bf(v.y) << 16);
        ((uint32_t*)xb)[i] = p;
    }
}

// =================== weight transposes (fp32 src -> bf16 transposed) ===================
__global__ void k_transpose_w1(const float* __restrict__ gw1,
                               const float* __restrict__ mw1,
                               unsigned short* __restrict__ W1t) {
    int idx = blockIdx.x * 256 + threadIdx.x;      // 6*65536
    int j = idx >> 16;
    int rem = idx & 65535;
    int n = rem >> 8, k = rem & 255;
    const float* src = (j < 3) ? (gw1 + (size_t)j * 65536)
                               : (mw1 + (size_t)(j - 3) * 65536);
    W1t[(size_t)idx] = f2bf(src[k * 256 + n]);
}
__global__ void k_transpose_wo(const float* __restrict__ mwo,
                               unsigned short* __restrict__ Wot) {
    int idx = blockIdx.x * 256 + threadIdx.x;      // 3*32768
    int h = idx / 32768;
    int rem = idx % 32768;
    int f = rem >> 8, k = rem & 255;
    Wot[idx] = f2bf(mwo[(size_t)h * 32768 + k * 128 + f]);
}

// =================== CSR build ===================
__global__ void k_hist(const int* __restrict__ idx, int* __restrict__ cnt) {
    int e = blockIdx.x * 256 + threadIdx.x;
    if (e < MM) atomicAdd(&cnt[idx[e]], 1);
}
__global__ void k_scan1(const int* __restrict__ cnt, int* __restrict__ pincl, int* __restrict__ bsum) {
    __shared__ int s[256];
    int t = threadIdx.x;
    int i = blockIdx.x * 256 + t;
    int v = (i < NN) ? cnt[i] : 0;
    s[t] = v; __syncthreads();
    for (int o = 1; o < 256; o <<= 1) {
        int add = (t >= o) ? s[t - o] : 0;
        __syncthreads();
        s[t] += add;
        __syncthreads();
    }
    if (i < NN) pincl[i] = s[t];
    if (t == 255) bsum[blockIdx.x] = s[255];
}
__global__ void k_scan2(const int* __restrict__ bsum, int* __restrict__ boff, int nb) {
    __shared__ int s[512];
    int t = threadIdx.x;
    int v = (t < nb) ? bsum[t] : 0;
    s[t] = v; __syncthreads();
    for (int o = 1; o < 512; o <<= 1) {
        int add = (t >= o) ? s[t - o] : 0;
        __syncthreads();
        s[t] += add;
        __syncthreads();
    }
    if (t < nb) boff[t] = s[t] - v;
}
__global__ void k_scan3(const int* __restrict__ pincl, const int* __restrict__ boff, int* __restrict__ rp) {
    int i = blockIdx.x * 256 + threadIdx.x;
    if (i < NN) rp[i + 1] = pincl[i] + boff[i >> 8];
    if (i == 0) rp[0] = 0;
}
__global__ void k_scatter(const int* __restrict__ self, const int* __restrict__ rp,
                          int* __restrict__ fill, int* __restrict__ elist) {
    int e = blockIdx.x * 256 + threadIdx.x;
    if (e < MM) {
        int n = self[e];
        int pos = atomicAdd(&fill[n], 1);
        elist[rp[n] + pos] = e;
    }
}
__global__ void k_perm(const int* __restrict__ elist, const int* __restrict__ self,
                       const int* __restrict__ nbr, int* __restrict__ selfp, int* __restrict__ nbrp) {
    int i = blockIdx.x * 256 + threadIdx.x;
    if (i < MM) {
        int e = elist[i];
        selfp[i] = self[e];
        nbrp[i] = nbr[e];
    }
}

// =================== colsum of fea (count-weighted node sums, fp32 x) ===================
__global__ void k_colsum(const float* __restrict__ x,
                         const int* __restrict__ cnt_self, const int* __restrict__ cnt_nbr,
                         float* __restrict__ colsum) {
    int t = threadIdx.x;
    int col = t & 127, part = t >> 7;
    const int* cp = part ? cnt_nbr : cnt_self;
    int n0 = blockIdx.x * 512;
    float a = 0.f;
    for (int i = 0; i < 512; i++) {
        int n = n0 + i;
        if (n < NN) {
            float c = (float)cp[n];
            a += c * x[(size_t)n * FD + col];
        }
    }
    atomicAdd(&colsum[part * 128 + col], a);
}

// =================== S = fea^T fea (Gram over edges, transposed LDS staging) ==========
// R11 lesson: splitting S into node-Gram + edge-Gram regressed (+70us: scalar weight
// fold + 2x atomics + extra dispatch overhead). Single edge-pass kernel restored;
// fed with CSR-permuted selfp/nbrp so the self-side gather is near-sequential in L2.
#define NCH 7813
#define CPB 62
__global__ __launch_bounds__(256, 2)
void k_S(const unsigned short* __restrict__ xb,
         const int* __restrict__ self_idx, const int* __restrict__ nbr_idx,
         float* __restrict__ S) {
    __shared__ unsigned short LT[256][72];   // [feat][edge 64 + pad8]
    const int tid = threadIdx.x;
    const int e_l = tid & 63;       // edge within chunk
    const int half = tid >> 6;      // feat group: half*64 .. +64
    const int ti = blockIdx.y >> 1, tj = blockIdx.y & 1;
    const int lane = tid & 63, w = tid >> 6;
    const int lr = lane & 15, q = lane >> 4;

    int cbeg = blockIdx.x * CPB;
    int cend = cbeg + CPB; if (cend > NCH) cend = NCH;

    floatx4 acc[2][8];
#pragma unroll
    for (int a = 0; a < 2; a++)
#pragma unroll
        for (int b = 0; b < 8; b++)
#pragma unroll
            for (int r = 0; r < 4; r++) acc[a][b][r] = 0.f;

    for (int ch = cbeg; ch < cend; ch++) {
        int e = ch * 64 + e_l;
        union { uint4 v[8]; unsigned short us[64]; } buf;
        if (e < MM) {
            int node = (half < 2) ? self_idx[e] : nbr_idx[e];
            const unsigned short* src = xb + (size_t)node * FD + (half & 1) * 64;
#pragma unroll
            for (int u2 = 0; u2 < 8; u2++) buf.v[u2] = *(const uint4*)(src + u2 * 8);
        } else {
#pragma unroll
            for (int u2 = 0; u2 < 8; u2++) { buf.v[u2].x = 0u; buf.v[u2].y = 0u; buf.v[u2].z = 0u; buf.v[u2].w = 0u; }
        }
        __syncthreads();   // prev MFMA reads done before overwrite
#pragma unroll
        for (int j2 = 0; j2 < 64; j2++)
            LT[half * 64 + j2][e_l] = buf.us[j2];
        __syncthreads();
#pragma unroll
        for (int ks = 0; ks < 64; ks += 32) {
            bf16x8 aF[2], bF[8];
#pragma unroll
            for (int mi = 0; mi < 2; mi++)
                aF[mi] = *(const bf16x8*)&LT[ti * 128 + w * 32 + mi * 16 + lr][ks + q * 8];
#pragma unroll
            for (int nj = 0; nj < 8; nj++)
                bF[nj] = *(const bf16x8*)&LT[tj * 128 + nj * 16 + lr][ks + q * 8];
#pragma unroll
            for (int mi = 0; mi < 2; mi++)
#pragma unroll
                for (int nj = 0; nj < 8; nj++)
                    acc[mi][nj] = __builtin_amdgcn_mfma_f32_16x16x32_bf16(aF[mi], bF[nj], acc[mi][nj], 0, 0, 0);
        }
    }
#pragma unroll
    for (int mi = 0; mi < 2; mi++)
#pragma unroll
        for (int nj = 0; nj < 8; nj++)
#pragma unroll
            for (int r = 0; r < 4; r++) {
                int row = ti * 128 + w * 32 + mi * 16 + q * 4 + r;
                int col = tj * 128 + nj * 16 + lr;
                atomicAdd(&S[row * 256 + col], acc[mi][nj][r]);
            }
}

// =================== per-net BN scale/shift from S + colsum ===================
__global__ void k_stats(const float* __restrict__ S, const float* __restrict__ colsum,
                        const unsigned short* __restrict__ W1t,
                        const float* __restrict__ gg, const float* __restrict__ gbe,
                        const float* __restrict__ mg, const float* __restrict__ mbe,
                        float* __restrict__ scaleA, float* __restrict__ shiftA) {
    __shared__ float ws[16][257];
    __shared__ float qq[16], uu[16];
    int t = threadIdx.x;
    int j = blockIdx.y;
    int c0 = blockIdx.x * 16;
    const unsigned short* Wn = W1t + (size_t)j * 65536;
    const float* g    = (j < 3) ? gg + j * 256 : mg + (j - 3) * 256;
    const float* beta = (j < 3) ? gbe + j * 256 : mbe + (j - 3) * 256;
#pragma unroll
    for (int i = 0; i < 16; i++) ws[i][t] = bf2f(Wn[(size_t)(c0 + i) * 256 + t]);
    if (t < 16) { qq[t] = 0.f; uu[t] = 0.f; }
    __syncthreads();
    float vpart[16];
#pragma unroll
    for (int i = 0; i < 16; i++) vpart[i] = 0.f;
    for (int k = 0; k < 256; k++) {
        float s = S[k * 256 + t];          // S symmetric: column read = (S w)_t
#pragma unroll
        for (int i = 0; i < 16; i++) vpart[i] += s * ws[i][k];
    }
    float cs = colsum[t];
    int lane = t & 63;
#pragma unroll
    for (int i = 0; i < 16; i++) {
        float q1 = ws[i][t] * vpart[i];
        float u1 = cs * ws[i][t];
#pragma unroll
        for (int m = 1; m <= 32; m <<= 1) { q1 += __shfl_xor(q1, m); u1 += __shfl_xor(u1, m); }
        if (lane == 0) { atomicAdd(&qq[i], q1); atomicAdd(&uu[i], u1); }
    }
    __syncthreads();
    if (t < 16) {
        int c = c0 + t;
        float mu = fin(uu[t] / (float)MM);
        float var = fmaxf(fin(qq[t] / (float)MM - mu * mu), 0.f);
        float sc = fin(g[c] * rsqrtf(var + 1e-5f));
        scaleA[j * 256 + c] = sc;
        shiftA[j * 256 + c] = fin(beta[c] - mu * sc);
    }
}

// =================== fused gate, ALL 3 HEADS (R3 skeleton + XCD swizzle) =============
__global__ __launch_bounds__(256, 2)
void k_gate(const unsigned short* __restrict__ x,
            const int* __restrict__ selfp, const int* __restrict__ nbrp,
            const unsigned short* __restrict__ W1t,     // gate nets base (3 * 65536)
            const float* __restrict__ scale, const float* __restrict__ shift,  // [3][256]
            const float* __restrict__ wo, const float* __restrict__ bo,        // [3][256], [3]
            float* __restrict__ glog) {                  // [3][MM]
    __shared__ unsigned char Bs[2][16384];   // linear, XOR-swizzled content
    __shared__ float sc[3][256], sh[3][256], wv[3][256];
    __shared__ int nid[128], nidN[128];

    const int tid = threadIdx.x;
    const int m0 = swz_bid(blockIdx.x, NTILES) * 128;
#pragma unroll
    for (int h = 0; h < 3; h++) {
        sc[h][tid] = scale[h * 256 + tid];
        sh[h][tid] = shift[h * 256 + tid];
        wv[h][tid] = wo[h * 256 + tid];
    }
    if (tid < 128) {
        int e = m0 + tid;
        nid[tid]  = (e < MM) ? selfp[e] : 0;
        nidN[tid] = (e < MM) ? nbrp[e] : 0;
    }
    __syncthreads();

    const int lane = tid & 63, w = tid >> 6;
    const int lr = lane & 15, q = lane >> 4;
    const int swz = (lr & 7) << 4;

    // ---- A fragments in registers: rows w*32+mi*16+lr, k = s*32+q*8 ----
    bf16x8 aReg[2][8];
    {
        const unsigned short* bS0 = x + (size_t)nid[w * 32 + lr] * FD;
        const unsigned short* bS1 = x + (size_t)nid[w * 32 + 16 + lr] * FD;
        const unsigned short* bN0 = x + (size_t)nidN[w * 32 + lr] * FD;
        const unsigned short* bN1 = x + (size_t)nidN[w * 32 + 16 + lr] * FD;
#pragma unroll
        for (int s = 0; s < 8; s++) {
            int koff = (s & 3) * 32 + q * 8;
            aReg[0][s] = *(const bf16x8*)(((s < 4) ? bS0 : bN0) + koff);
            aReg[1][s] = *(const bf16x8*)(((s < 4) ? bS1 : bN1) + koff);
        }
    }

    // staging source offsets (bytes): linear dest o -> pre-swizzled source
    uint32_t pre[4];
#pragma unroll
    for (int c = 0; c < 4; c++) {
        int o = (w * 4 + c) * 1024 + lane * 16;
        int r = o >> 7, lc = o & 127;
        pre[c] = (uint32_t)(r * 512 + (lc ^ ((r & 7) << 4)));
    }

    auto STAGE = [&](int t, int b) {
        int hh = t >> 3, rr = t & 7, nh2 = rr >> 2, kc = rr & 3;
        const char* gb = (const char*)(W1t + (size_t)hh * 65536 + (size_t)nh2 * 32768 + kc * 64);
#pragma unroll
        for (int c = 0; c < 4; c++)
            gl_lds16(gb + pre[c], &Bs[b][(w * 4 + c) * 1024]);
    };

    STAGE(0, 0);
    vm_drain();
    __syncthreads();

    int buf = 0, tcur = 0;
    for (int h = 0; h < 3; h++) {
        float dotp[2][4];
#pragma unroll
        for (int mi = 0; mi < 2; mi++)
#pragma unroll
            for (int r = 0; r < 4; r++) dotp[mi][r] = 0.f;

        for (int nh = 0; nh < 2; nh++) {
            floatx4 acc[2][8];
#pragma unroll
            for (int a = 0; a < 2; a++)
#pragma unroll
                for (int b = 0; b < 8; b++)
#pragma unroll
                    for (int r = 0; r < 4; r++) acc[a][b][r] = 0.f;

#pragma unroll
            for (int kc = 0; kc < 4; kc++) {
                if (tcur + 1 < 24) STAGE(tcur + 1, buf ^ 1);
#pragma unroll
                for (int ks = 0; ks < 2; ks++) {
                    bf16x8 bF[8];
#pragma unroll
                    for (int nj = 0; nj < 8; nj++)
                        bF[nj] = *(const bf16x8*)&Bs[buf][(nj * 16 + lr) * 128 + ((ks * 64 + q * 16) ^ swz)];
                    __builtin_amdgcn_s_setprio(1);
#pragma unroll
                    for (int mi = 0; mi < 2; mi++)
#pragma unroll
                        for (int nj = 0; nj < 8; nj++)
                            acc[mi][nj] = __builtin_amdgcn_mfma_f32_16x16x32_bf16(aReg[mi][kc * 2 + ks], bF[nj], acc[mi][nj], 0, 0, 0);
                    __builtin_amdgcn_s_setprio(0);
                }
                vm_drain();
                __syncthreads();
                buf ^= 1; tcur++;
            }
            // fold BN+SiLU+Wo dot into dotp
#pragma unroll
            for (int mi = 0; mi < 2; mi++)
#pragma unroll
                for (int r = 0; r < 4; r++) {
                    float d = 0.f;
#pragma unroll
                    for (int nj = 0; nj < 8; nj++) {
                        int cg = nh * 128 + nj * 16 + lr;
                        float v = acc[mi][nj][r] * sc[h][cg] + sh[h][cg];
                        d += silu(v) * wv[h][cg];
                    }
                    dotp[mi][r] += d;
                }
        }
        float b0 = bo[h];
#pragma unroll
        for (int mi = 0; mi < 2; mi++)
#pragma unroll
            for (int r = 0; r < 4; r++) {
                float v = dotp[mi][r];
                v += __shfl_xor(v, 1); v += __shfl_xor(v, 2);
                v += __shfl_xor(v, 4); v += __shfl_xor(v, 8);
                if (lr == 0) {
                    int row = w * 32 + mi * 16 + q * 4 + r;
                    int e = m0 + row;
                    if (e < MM) glog[(size_t)h * MM + e] = fin(v + b0);
                }
            }
    }
}

// =================== softmax coefficients per node (head-parallel) ===================
__global__ void k_coef(const int* __restrict__ rp, const float* __restrict__ glog,
                       float* __restrict__ coef, const float* __restrict__ ew,
                       const int* __restrict__ nbrp, const float* __restrict__ powp) {
    int n = blockIdx.x * 256 + threadIdx.x;
    if (n >= NN) return;
    int b = rp[n], e = rp[n + 1];
    if (e <= b) return;
    int h = blockIdx.y;
    const float* gl = glog + (size_t)h * MM;
    float* cf = coef + (size_t)h * MM;
    float p = powp[h];
    float gmax = -3.4e38f;
    for (int i = b; i < e; i++) gmax = fmaxf(gmax, gl[i]);
    float den = 0.f;
    for (int i = b; i < e; i++) {
        float wvv = ew[nbrp[i]];
        float u = fin(powf(wvv, p) * __expf(gl[i] - gmax));
        cf[i] = u; den += u;
    }
    float inv = fin(1.f / (den + 1e-10f));
    for (int i = b; i < e; i++) cf[i] = fin(cf[i] * inv);
}

// =================== fused msg, ALL 3 HEADS (exact R3 skeleton incl. div-silu) =======
__global__ __launch_bounds__(256, 2)
void k_msg(const unsigned short* __restrict__ x,
           const int* __restrict__ selfp, const int* __restrict__ nbrp,
           const unsigned short* __restrict__ W1t,       // msg nets base (3 * 65536)
           const float* __restrict__ scale, const float* __restrict__ shift,   // [3][256]
           const unsigned short* __restrict__ Wo2t,      // [3][128 f][256 k]
           const float* __restrict__ bo2,                // [3][128]
           const float* __restrict__ coef,               // [3][MM] perm order
           float* __restrict__ out_acc) {
    __shared__ unsigned char Bs[2][16384];   // linear, XOR-swizzled content
    __shared__ unsigned short ActC[128][72];
    __shared__ float sc[3][256], sh[3][256];
    __shared__ float bvec[3][128], cfs[3][128];
    __shared__ int nid[128], nidN[128];

    const int tid = threadIdx.x;
    const int m0 = blockIdx.x * 128;
#pragma unroll
    for (int h = 0; h < 3; h++) {
        sc[h][tid] = scale[h * 256 + tid];
        sh[h][tid] = shift[h * 256 + tid];
    }
    if (tid < 128) {
        int e = m0 + tid;
        nid[tid]  = (e < MM) ? selfp[e] : -1;
        nidN[tid] = (e < MM) ? nbrp[e] : 0;
#pragma unroll
        for (int h = 0; h < 3; h++) {
            bvec[h][tid] = bo2[h * 128 + tid];
            cfs[h][tid] = (e < MM) ? coef[(size_t)h * MM + e] : 0.f;
        }
    }
    __syncthreads();

    const int lane = tid & 63, w = tid >> 6;
    const int lr = lane & 15, q = lane >> 4;
    const int swz = (lr & 7) << 4;

    // ---- A fragments in registers ----
    bf16x8 aReg[2][8];
    {
        int nS0 = nid[w * 32 + lr];      if (nS0 < 0) nS0 = 0;
        int nS1 = nid[w * 32 + 16 + lr]; if (nS1 < 0) nS1 = 0;
        const unsigned short* bS0 = x + (size_t)nS0 * FD;
        const unsigned short* bS1 = x + (size_t)nS1 * FD;
        const unsigned short* bN0 = x + (size_t)nidN[w * 32 + lr] * FD;
        const unsigned short* bN1 = x + (size_t)nidN[w * 32 + 16 + lr] * FD;
#pragma unroll
        for (int s = 0; s < 8; s++) {
            int koff = (s & 3) * 32 + q * 8;
            aReg[0][s] = *(const bf16x8*)(((s < 4) ? bS0 : bN0) + koff);
            aReg[1][s] = *(const bf16x8*)(((s < 4) ? bS1 : bN1) + koff);
        }
    }

    uint32_t pre[4];
#pragma unroll
    for (int c = 0; c < 4; c++) {
        int o = (w * 4 + c) * 1024 + lane * 16;
        int r = o >> 7, lc = o & 127;
        pre[c] = (uint32_t)(r * 512 + (lc ^ ((r & 7) << 4)));
    }

    // tile t in 0..35: hh = t/12, rr = t%12, nh = rr/6, s6 = rr%6
    // s6<4 -> W1 tile (kc=s6); else Wo2 tile (kc2=s6-4)
    auto STAGE = [&](int t, int b) {
        int hh = t / 12, rr = t % 12, nh2 = rr / 6, s6 = rr % 6;
        const unsigned short* base = (s6 < 4)
            ? (W1t + (size_t)hh * 65536 + (size_t)nh2 * 32768 + s6 * 64)
            : (Wo2t + (size_t)hh * 32768 + nh2 * 128 + (s6 - 4) * 64);
        const char* gb = (const char*)base;
#pragma unroll
        for (int c = 0; c < 4; c++)
            gl_lds16(gb + pre[c], &Bs[b][(w * 4 + c) * 1024]);
    };

    STAGE(0, 0);
    vm_drain();
    __syncthreads();

    floatx4 acc2[2][8];   // combined accumulator over all 3 heads (coef-weighted)
#pragma unroll
    for (int a = 0; a < 2; a++)
#pragma unroll
        for (int b = 0; b < 8; b++)
#pragma unroll
            for (int r = 0; r < 4; r++) acc2[a][b][r] = 0.f;

    int buf = 0, tcur = 0;
    for (int h = 0; h < 3; h++) {
        float cfr[2][4];
#pragma unroll
        for (int mi = 0; mi < 2; mi++)
#pragma unroll
            for (int r = 0; r < 4; r++) cfr[mi][r] = cfs[h][w * 32 + mi * 16 + q * 4 + r];

        for (int nh = 0; nh < 2; nh++) {
            floatx4 acc[2][8];
#pragma unroll
            for (int a = 0; a < 2; a++)
#pragma unroll
                for (int b = 0; b < 8; b++)
#pragma unroll
                    for (int r = 0; r < 4; r++) acc[a][b][r] = 0.f;

#pragma unroll
            for (int kc = 0; kc < 4; kc++) {
                if (tcur + 1 < 36) STAGE(tcur + 1, buf ^ 1);
#pragma unroll
                for (int ks = 0; ks < 2; ks++) {
                    bf16x8 bF[8];
#pragma unroll
                    for (int nj = 0; nj < 8; nj++)
                        bF[nj] = *(const bf16x8*)&Bs[buf][(nj * 16 + lr) * 128 + ((ks * 64 + q * 16) ^ swz)];
                    __builtin_amdgcn_s_setprio(1);
#pragma unroll
                    for (int mi = 0; mi < 2; mi++)
#pragma unroll
                        for (int nj = 0; nj < 8; nj++)
                            acc[mi][nj] = __builtin_amdgcn_mfma_f32_16x16x32_bf16(aReg[mi][kc * 2 + ks], bF[nj], acc[mi][nj], 0, 0, 0);
                    __builtin_amdgcn_s_setprio(0);
                }
                vm_drain();
                __syncthreads();
                buf ^= 1; tcur++;
            }
#pragma unroll
            for (int kc2 = 0; kc2 < 2; kc2++) {
                if (tcur + 1 < 36) STAGE(tcur + 1, buf ^ 1);
                // activations: rows w*32..+31 are written AND read by this wave only
#pragma unroll
                for (int mi = 0; mi < 2; mi++)
#pragma unroll
                    for (int njl = 0; njl < 4; njl++)
#pragma unroll
                        for (int r = 0; r < 4; r++) {
                            int nj = kc2 * 4 + njl;
                            int row = w * 32 + mi * 16 + q * 4 + r;
                            int cg = nh * 128 + nj * 16 + lr;
                            float v = acc[mi][nj][r] * sc[h][cg] + sh[h][cg];
                            ActC[row][njl * 16 + lr] = f2bf_hw(silu_div(v) * cfr[mi][r]);
                        }
#pragma unroll
                for (int ks = 0; ks < 2; ks++) {
                    bf16x8 aF[2], bF[8];
#pragma unroll
                    for (int mi = 0; mi < 2; mi++)
                        aF[mi] = *(const bf16x8*)&ActC[w * 32 + mi * 16 + lr][ks * 32 + q * 8];
#pragma unroll
                    for (int nj = 0; nj < 8; nj++)
                        bF[nj] = *(const bf16x8*)&Bs[buf][(nj * 16 + lr) * 128 + ((ks * 64 + q * 16) ^ swz)];
                    __builtin_amdgcn_s_setprio(1);
#pragma unroll
                    for (int mi = 0; mi < 2; mi++)
#pragma unroll
                        for (int nj = 0; nj < 8; nj++)
                            acc2[mi][nj] = __builtin_amdgcn_mfma_f32_16x16x32_bf16(aF[mi], bF[nj], acc2[mi][nj], 0, 0, 0);
                    __builtin_amdgcn_s_setprio(0);
                }
                vm_drain();
                __syncthreads();
                buf ^= 1; tcur++;
            }
        }
    }
    // ---- epilogue: single combined atomic scatter; bias term = sum_h cf_h[row]*b_h[col]
#pragma unroll
    for (int mi = 0; mi < 2; mi++) {
        int rbase = w * 32 + mi * 16 + q * 4;
        int n0 = nid[rbase], n3 = nid[rbase + 3];
        float c0[3], c1[3], c2[3], c3[3];
#pragma unroll
        for (int h = 0; h < 3; h++) {
            c0[h] = cfs[h][rbase];     c1[h] = cfs[h][rbase + 1];
            c2[h] = cfs[h][rbase + 2]; c3[h] = cfs[h][rbase + 3];
        }
#pragma unroll
        for (int nj = 0; nj < 8; nj++) {
            int col = nj * 16 + lr;
            float b0h = bvec[0][col], b1h = bvec[1][col], b2h = bvec[2][col];
            float v0 = acc2[mi][nj][0] + c0[0] * b0h + c0[1] * b1h + c0[2] * b2h;
            float v1 = acc2[mi][nj][1] + c1[0] * b0h + c1[1] * b1h + c1[2] * b2h;
            float v2 = acc2[mi][nj][2] + c2[0] * b0h + c2[1] * b1h + c2[2] * b2h;
            float v3 = acc2[mi][nj][3] + c3[0] * b0h + c3[1] * b1h + c3[2] * b2h;
            if (n0 == n3) {
                if (n0 >= 0) atomicAdd(&out_acc[(size_t)n0 * FD + col], v0 + v1 + v2 + v3);
            } else {
                int n1 = nid[rbase + 1], n2 = nid[rbase + 2];
                if (n0 >= 0) atomicAdd(&out_acc[(size_t)n0 * FD + col], v0);
                if (n1 >= 0) atomicAdd(&out_acc[(size_t)n1 * FD + col], v1);
                if (n2 >= 0) atomicAdd(&out_acc[(size_t)n2 * FD + col], v2);
                if (n3 >= 0) atomicAdd(&out_acc[(size_t)n3 * FD + col], v3);
            }
        }
    }
}

// =================== final (in place): out = out/3 + x ===================
__global__ void k_finalout(float* __restrict__ out, const float* __restrict__ x) {
    int i = blockIdx.x * 256 + threadIdx.x;
    if (i < NN * FD) out[i] = fin(out[i]) * (1.f / 3.f) + x[i];
}

extern "C" void kernel_launch(void* const* d_in, const int* in_sizes, int n_in,
                              void* d_out, int out_size, void* d_ws, size_t ws_size,
                              hipStream_t stream) {
    const float* ew   = (const float*)d_in[0];
    const float* x    = (const float*)d_in[1];
    const float* gW1  = (const float*)d_in[2];
    const float* gg   = (const float*)d_in[4];
    const float* gbe  = (const float*)d_in[5];
    const float* gWo  = (const float*)d_in[6];
    const float* gbo  = (const float*)d_in[7];
    const float* mW1  = (const float*)d_in[8];
    const float* mg   = (const float*)d_in[10];
    const float* mbe  = (const float*)d_in[11];
    const float* mWo  = (const float*)d_in[12];
    const float* mbo  = (const float*)d_in[13];
    const float* powp = (const float*)d_in[14];
    const int* self_idx = (const int*)d_in[15];
    const int* nbr_idx  = (const int*)d_in[16];
    float* out = (float*)d_out;

    char* ws = (char*)d_ws;
    size_t off = 0;
    auto alloc = [&](size_t bytes) -> void* {
        size_t o = off;
        off += (bytes + 255) & ~(size_t)255;
        return (void*)(ws + o);
    };

    // ---- zero span (contiguous) ----
    float* S       = (float*)alloc(256 * 256 * 4);
    float* colsum  = (float*)alloc(512 * 4);
    int*   cnt     = (int*)alloc((size_t)NN * 4);
    int*   cntn    = (int*)alloc((size_t)NN * 4);
    int*   fill    = (int*)alloc((size_t)NN * 4);
    size_t zero_end = off;
    // ---- rest ----
    unsigned short* xb   = (unsigned short*)alloc((size_t)NN * FD * 2);
    unsigned short* W1t  = (unsigned short*)alloc(6ull * 65536 * 2);
    unsigned short* Wo2t = (unsigned short*)alloc(3ull * 32768 * 2);
    float* scaleA = (float*)alloc(6ull * 256 * 4);
    float* shiftA = (float*)alloc(6ull * 256 * 4);
    int*   rp     = (int*)alloc((size_t)(NN + 1) * 4);
    int*   pincl  = (int*)alloc((size_t)NN * 4);
    int*   bsum   = (int*)alloc(512 * 4);
    int*   boff   = (int*)alloc(512 * 4);
    int*   elist  = (int*)alloc((size_t)MM * 4);
    int*   selfp  = (int*)alloc((size_t)MM * 4);
    int*   nbrp   = (int*)alloc((size_t)MM * 4);
    float* glog   = (float*)alloc(3ull * MM * 4);
    float* coef   = (float*)alloc(3ull * MM * 4);
    if (off > ws_size) return;   // ~47 MB needed

    int zwords = (int)(zero_end / 4);
    k_zero<<<(zwords + 255) / 256, 256, 0, stream>>>(S, zwords);
    k_zero<<<(NN * FD + 255) / 256, 256, 0, stream>>>(out, NN * FD);  // out = accumulator

    k_castx<<<(NN * FD / 2 + 255) / 256, 256, 0, stream>>>(x, xb);
    k_transpose_w1<<<1536, 256, 0, stream>>>(gW1, mW1, W1t);
    k_transpose_wo<<<384, 256, 0, stream>>>(mWo, Wo2t);

    k_hist<<<1954, 256, 0, stream>>>(self_idx, cnt);
    k_hist<<<1954, 256, 0, stream>>>(nbr_idx, cntn);
    int nb1 = (NN + 255) / 256;   // 391
    k_scan1<<<nb1, 256, 0, stream>>>(cnt, pincl, bsum);
    k_scan2<<<1, 512, 0, stream>>>(bsum, boff, nb1);
    k_scan3<<<nb1, 256, 0, stream>>>(pincl, boff, rp);
    k_scatter<<<1954, 256, 0, stream>>>(self_idx, rp, fill, elist);
    k_perm<<<1954, 256, 0, stream>>>(elist, self_idx, nbr_idx, selfp, nbrp);

    k_colsum<<<(NN + 511) / 512, 256, 0, stream>>>(x, cnt, cntn, colsum);
    // S over CSR-permuted edges: self-side gather near-sequential, L2-warm
    k_S<<<dim3(128, 4), 256, 0, stream>>>(xb, selfp, nbrp, S);
    k_stats<<<dim3(16, 6), 256, 0, stream>>>(S, colsum, W1t, gg, gbe, mg, mbe, scaleA, shiftA);

    // fused 3-head gate (one dispatch)
    k_gate<<<NTILES, 256, 0, stream>>>(xb, selfp, nbrp, W1t,
                                       scaleA, shiftA, gWo, gbo, glog);
    k_coef<<<dim3(nb1, 3), 256, 0, stream>>>(rp, glog, coef, ew, nbrp, powp);
    // fused 3-head msg (one dispatch, single combined atomic epilogue)
    k_msg<<<NTILES, 256, 0, stream>>>(xb, selfp, nbrp, W1t + 3ull * 65536,
                                      scaleA + 3 * 256, shiftA + 3 * 256,
                                      Wo2t, mbo, coef, out);
    k_finalout<<<(NN * FD + 255) / 256, 256, 0, stream>>>(out, x);
}